// Round 10
// baseline (277.110 us; speedup 1.0000x reference)
//
#include <hip/hip_runtime.h>
#include <hip/hip_bf16.h>

#define N_ 384
#define C_ 128
#define M_ (N_*N_)   // 147456 rows (i*384+j)

typedef __attribute__((ext_vector_type(8))) short bf16x8_t;
typedef __attribute__((ext_vector_type(4))) float f32x4_t;
typedef unsigned int u32;
typedef unsigned short u16;
typedef unsigned long long u64;

__device__ __forceinline__ u16 f2bf(float f) {
  u32 u = __builtin_bit_cast(u32, f);
  u32 r = (u + 0x7FFFu + ((u >> 16) & 1u)) >> 16;
  return (u16)r;
}
__device__ __forceinline__ float bf2f(u16 h) {
  u32 u = ((u32)h) << 16;
  return __builtin_bit_cast(float, u);
}
// RNE pack of 2 f32 -> 2 bf16 in one VALU instruction (no builtin on gfx950; T12 recipe).
// dst[15:0] = bf16(lo), dst[31:16] = bf16(hi) — same layout as f2bf(lo) | f2bf(hi)<<16.
__device__ __forceinline__ u32 pk2bf(float lo, float hi) {
  u32 r;
  asm("v_cvt_pk_bf16_f32 %0, %1, %2" : "=v"(r) : "v"(lo), "v"(hi));
  return r;
}

// ---------------- fused prep kernel ----------------
__global__ __launch_bounds__(256) void k_prep(const float* __restrict__ lg, const float* __restrict__ rg,
    const float* __restrict__ Wl, const float* __restrict__ Wr, const float* __restrict__ Wg,
    const float* __restrict__ Wo,
    const float* __restrict__ lb, const float* __restrict__ rb,
    const float* __restrict__ bl, const float* __restrict__ br, const float* __restrict__ bg,
    u16* __restrict__ wcat, u16* __restrict__ wot,
    float* __restrict__ bcat, float* __restrict__ csum) {
  int bx = blockIdx.x, t = threadIdx.x;
  if (bx < 256) {
    int idx = bx*256 + t;
    if (idx < 49152) {
      int n = idx >> 7, k = idx & 127;
      float v;
      if (n < 128)      v = lg[k] * Wl[k*128 + n];
      else if (n < 256) v = rg[k] * Wr[k*128 + (n-128)];
      else              v = Wg[k*128 + (n-256)];
      wcat[idx] = f2bf(v);
    } else {
      int i2 = idx - 49152;           // < 16384
      int c = i2 >> 7, h = i2 & 127;
      wot[i2] = f2bf(Wo[h*128 + c]);
    }
  } else if (bx == 256) {
    float s = 0.f;
    if (t < 128)      { for (int k=0;k<128;k++) s += lb[k]*Wl[k*128+t];       s += bl[t];     bcat[t] = s; }
    else              { int hh=t-128; for (int k=0;k<128;k++) s += rb[k]*Wr[k*128+hh]; s += br[hh]; bcat[t] = s; }
  } else { // bx == 257
    if (t < 128) bcat[256+t] = bg[t];
    float s = 0.f;
    if (t < 128) {
      for (int k=0;k<128;k++) s += bf2f(f2bf(lg[k]*Wl[k*128+t]));
      csum[t] = s;
    } else {
      int hh = t-128;
      for (int k=0;k<128;k++) s += bf2f(f2bf(rg[k]*Wr[k*128+hh]));
      csum[128+hh] = s;
    }
  }
}

#define LDK 136  // u16 stride of staged 128-k rows
#define LDA 72
#define LDW 72
#define LDW2 136
#define LDT 136

// ---------------- K1: LN-folded proj, 256 threads / 4 waves ----------------
// Identical structure to round 9; all bf16 pack sites now use v_cvt_pk_bf16_f32
// (1 VALU inst / 2 values vs ~10 for the hand-rolled RNE sequence). ~400 VALU
// ops/thread removed from the busiest pipe (VALUBusy 26%).
__global__ __launch_bounds__(256) void k_projln(const float* __restrict__ pair,
    const u16* __restrict__ wcat, const float* __restrict__ bcat, const float* __restrict__ csum,
    u16* __restrict__ lr_, u16* __restrict__ gate_) {
  __shared__ u16 At[128*LDK];   // 34816 B
  __shared__ float mu_s[128];
  __shared__ float rstd_s[128];
  int bx = blockIdx.x;
  int t = threadIdx.x, w = t>>6, lane = t&63;
  int q = lane>>4, nl = lane&15;
  int r0 = bx * 128;

  // ---- load + raw-stage + moments: 4 thr/row, 2 passes of 64 rows ----
  #pragma unroll
  for (int pass=0; pass<2; ++pass) {
    int rr = pass*64 + (t>>2), quarter = t&3;
    const float4* gp = (const float4*)(pair + (size_t)(r0+rr)*128 + quarter*32);
    u32* lp = (u32*)(At + rr*LDK + quarter*32);
    float s = 0.f, qq = 0.f;
    #pragma unroll
    for (int i=0;i<4;i++) {
      float4 a = gp[2*i];
      float4 b = gp[2*i+1];
      s  += a.x + a.y + a.z + a.w + b.x + b.y + b.z + b.w;
      qq += a.x*a.x + a.y*a.y + a.z*a.z + a.w*a.w
          + b.x*b.x + b.y*b.y + b.z*b.z + b.w*b.w;
      u32 p0 = pk2bf(a.x, a.y);
      u32 p1 = pk2bf(a.z, a.w);
      u32 p2 = pk2bf(b.x, b.y);
      u32 p3 = pk2bf(b.z, b.w);
      ((uint4*)lp)[i] = make_uint4(p0,p1,p2,p3);
    }
    s  += __shfl_xor(s, 1, 64);
    s  += __shfl_xor(s, 2, 64);
    qq += __shfl_xor(qq, 1, 64);
    qq += __shfl_xor(qq, 2, 64);
    if (quarter == 0) {
      float mu = s * (1.f/128.f);
      float var = qq*(1.f/128.f) - mu*mu;
      mu_s[rr] = mu;
      rstd_s[rr] = rsqrtf(var + 1e-5f);
    }
  }
  __syncthreads();

  #pragma unroll 1
  for (int nb = 0; nb < 3; ++nb) {
    #pragma unroll 1
    for (int nh = 0; nh < 2; ++nh) {
      int n = nh*64 + w*16 + nl;
      const u16* brow = wcat + (size_t)(nb*128 + n)*128;
      f32x4_t acc[8] = {};   // [tm] ; m = tm*16+q*4+p
      #pragma unroll
      for (int ks=0; ks<4; ks++) {
        int kel = ks*32 + q*8;
        bf16x8_t b = *(const bf16x8_t*)(brow + kel);
        #pragma unroll
        for (int tm=0;tm<8;tm++) {
          bf16x8_t a = *(const bf16x8_t*)(At + (tm*16+nl)*LDK + kel);
          acc[tm] = __builtin_amdgcn_mfma_f32_16x16x32_bf16(a, b, acc[tm], 0,0,0);
        }
      }
      float bias = bcat[nb*128 + n];
      u16* rowp;
      if (nb == 0)      rowp = lr_   + ((size_t)bx*256 + n)*128;
      else if (nb == 1) rowp = lr_   + ((size_t)bx*256 + 128 + n)*128;
      else              rowp = gate_ + ((size_t)bx*128 + n)*128;
      if (nb == 2) {
        #pragma unroll
        for (int tm=0;tm<8;tm++) {
          float v0 = acc[tm][0] + bias;
          float v1 = acc[tm][1] + bias;
          float v2 = acc[tm][2] + bias;
          float v3 = acc[tm][3] + bias;
          v0 = 1.0f/(1.0f+__expf(-v0));
          v1 = 1.0f/(1.0f+__expf(-v1));
          v2 = 1.0f/(1.0f+__expf(-v2));
          v3 = 1.0f/(1.0f+__expf(-v3));
          u32 pk0 = pk2bf(v0, v1);
          u32 pk1 = pk2bf(v2, v3);
          *(u64*)(rowp + tm*16 + q*4) = (u64)pk0 | ((u64)pk1<<32);
        }
      } else {
        float csn = csum[nb*128 + n];
        #pragma unroll
        for (int tm=0;tm<8;tm++) {
          f32x4_t mu4 = *(const f32x4_t*)(mu_s   + tm*16 + q*4);
          f32x4_t rs4 = *(const f32x4_t*)(rstd_s + tm*16 + q*4);
          float v0 = (acc[tm][0] - mu4[0]*csn)*rs4[0] + bias;
          float v1 = (acc[tm][1] - mu4[1]*csn)*rs4[1] + bias;
          float v2 = (acc[tm][2] - mu4[2]*csn)*rs4[2] + bias;
          float v3 = (acc[tm][3] - mu4[3]*csn)*rs4[3] + bias;
          u32 pk0 = pk2bf(v0, v1);
          u32 pk1 = pk2bf(v2, v3);
          *(u64*)(rowp + tm*16 + q*4) = (u64)pk0 | ((u64)pk1<<32);
        }
      }
    }
  }
}

// ---------------- K2: triangle einsum per h + gate multiply ----------------
// Unchanged except gate-multiply store uses v_cvt_pk_bf16_f32.
__global__ __launch_bounds__(512) void k_einsum(const u16* __restrict__ lr_,
    const u16* __restrict__ gate_, u16* __restrict__ og_) {
  __shared__ u16 smem[2*128*LDA];  // 36864 B
  u16* At = smem; u16* Bt = smem + 128*LDA;
  int bx = blockIdx.x;
  int wk = (bx & 7) * 144 + (bx >> 3);   // XCD-chunked bijection on 1152
  int h = wk / 9; int rem = wk % 9;
  int i0 = (rem/3)*128, j0c = rem%3;     // j0 = j0c*128
  int t = threadIdx.x, w = t>>6, lane = t&63;
  int q = lane>>4, nl = lane&15;
  f32x4_t acc[4][2] = {};
  int m0 = (w&1)*64, nb0 = (w>>1)*32;

  int rrA = t>>2, quarterA = t&3;        // A staging ids
  int kk2 = t>>4, seg = t&15;            // B staging ids

  uint4 aR0, aR1, bR0, bR1;
  { // prologue: loads for step 0 (kb=0 -> c=0, off=0)
    const u16* ga = lr_ + (((size_t)(i0+rrA)*3 + 0)*256 + h)*128 + quarterA*16;
    aR0 = ((const uint4*)ga)[0]; aR1 = ((const uint4*)ga)[1];
    const u16* g0 = lr_ + (((size_t)(2*kk2)*3 + j0c)*256 + 128 + h)*128 + seg*8;
    bR0 = ((const uint4*)g0)[0];
    bR1 = ((const uint4*)(g0 + 3*256*128))[0];
  }
  #pragma unroll 1
  for (int s = 0; s < 6; ++s) {
    { // write A tile from regs
      u16* lp = At + rrA*LDA + quarterA*16;
      ((uint4*)lp)[0] = aR0; ((uint4*)lp)[1] = aR1;
    }
    { // write B tile: register pair-transpose + XOR swizzle
      u32 w0[4] = {bR0.x,bR0.y,bR0.z,bR0.w};
      u32 w1[4] = {bR1.x,bR1.y,bR1.z,bR1.w};
      u32 sw = (u32)(seg>>1) << 4;
      char* bbytes = (char*)Bt;
      #pragma unroll
      for (int e=0;e<4;e++) {
        u32 lo = w0[e], hi = w1[e];
        u32 evenw = (lo & 0xffffu) | (hi << 16);
        u32 oddw  = (lo >> 16)     | (hi & 0xffff0000u);
        int je = seg*8 + 2*e;
        *(u32*)(bbytes + (((u32)(je*LDA + 2*kk2) * 2u) ^ sw)) = evenw;
        *(u32*)(bbytes + (((u32)((je+1)*LDA + 2*kk2) * 2u) ^ sw)) = oddw;
      }
    }
    if (s < 5) { // T14: issue next-step loads NOW (in flight through bar+MFMA+bar)
      int kb = (s+1)*64; int c = kb>>7, off = kb&127;
      const u16* ga = lr_ + (((size_t)(i0+rrA)*3 + c)*256 + h)*128 + off + quarterA*16;
      aR0 = ((const uint4*)ga)[0]; aR1 = ((const uint4*)ga)[1];
      const u16* g0 = lr_ + (((size_t)(kb + 2*kk2)*3 + j0c)*256 + 128 + h)*128 + seg*8;
      bR0 = ((const uint4*)g0)[0];
      bR1 = ((const uint4*)(g0 + 3*256*128))[0];
    }
    __syncthreads();
    #pragma unroll
    for (int ks=0; ks<2; ks++) {
      int kel = ks*32 + q*8;
      bf16x8_t a[4], b[2];
      #pragma unroll
      for (int tm=0;tm<4;tm++) a[tm] = *(const bf16x8_t*)(At + (m0+tm*16+nl)*LDA + kel);
      #pragma unroll
      for (int tn=0;tn<2;tn++) {
        u32 swr = (u32)(((nb0>>4) + tn) & 7) << 4;
        b[tn] = *(const bf16x8_t*)((const char*)Bt + ((u32)(((nb0+tn*16+nl)*LDA + kel)*2) ^ swr));
      }
      #pragma unroll
      for (int tm=0;tm<4;tm++)
        #pragma unroll
        for (int tn=0;tn<2;tn++)
          acc[tm][tn] = __builtin_amdgcn_mfma_f32_16x16x32_bf16(a[tm], b[tn], acc[tm][tn], 0,0,0);
    }
    __syncthreads();
  }
  // epilogue: acc -> LDS bf16 [m][n], then gate-multiplied coalesced store (og[rb][h][j])
  u16* Ot = smem;  // 128*LDT u16 = 34816 B <= 36864
  #pragma unroll
  for (int tm=0;tm<4;tm++)
    #pragma unroll
    for (int tn=0;tn<2;tn++)
      #pragma unroll
      for (int p=0;p<4;p++) {
        int m = m0 + tm*16 + q*4 + p;
        int n = nb0 + tn*16 + nl;
        Ot[m*LDT + n] = f2bf(acc[tm][tn][p]);
      }
  __syncthreads();
  {
    int m = t>>2, hq = t&3;
    size_t gbase = (((size_t)(i0+m)*3 + j0c)*128 + h)*128 + hq*32;
    const uint4* gg = (const uint4*)(gate_ + gbase);
    const uint4* lo = (const uint4*)(Ot + m*LDT + hq*32);
    uint4* od = (uint4*)(og_ + gbase);
    #pragma unroll
    for (int i=0;i<4;i++) {
      uint4 gv = gg[i]; uint4 ov = lo[i];
      u32 ga[4] = {gv.x,gv.y,gv.z,gv.w};
      u32 oa[4] = {ov.x,ov.y,ov.z,ov.w};
      u32 ra2[4];
      #pragma unroll
      for (int e=0;e<4;e++) {
        float g0 = bf2f((u16)(ga[e]&0xffffu)), g1 = bf2f((u16)(ga[e]>>16));
        float o0 = bf2f((u16)(oa[e]&0xffffu)), o1 = bf2f((u16)(oa[e]>>16));
        ra2[e] = pk2bf(o0*g0, o1*g1);
      }
      od[i] = make_uint4(ra2[0],ra2[1],ra2[2],ra2[3]);
    }
  }
}

// ---------------- K3: og @ Wo + bo + pair, rowwise LN, fp32 out (unchanged control) ----------------
__global__ __launch_bounds__(512) void k_final(const u16* __restrict__ og_, const u16* __restrict__ wot,
    const float* __restrict__ pair, const float* __restrict__ bo,
    const float* __restrict__ ng, const float* __restrict__ nb_,
    float* __restrict__ out) {
  __shared__ u16 At[128*LDW];    // 18432 B
  __shared__ u16 Wt[128*LDW2];   // 34816 B
  int bx = blockIdx.x;
  int r0 = bx * 128;
  int t = threadIdx.x, w = t>>6, lane = t&63;
  int q = lane>>4, nl = lane&15;
  f32x4_t acc[8] = {};
  int m0 = w*16;
  int hh2 = t>>4, seg = t&15;    // A staging: column pair 2*hh2, r-chunk seg*8

  uint4 aR0, aR1;
  { // prologue: A(c0=0) loads
    const u16* g0 = og_ + ((size_t)bx*128 + 2*hh2)*128 + seg*8;
    aR0 = ((const uint4*)g0)[0];
    aR1 = ((const uint4*)(g0 + 128))[0];
  }
  { // stage full Wo -> Wt[c][k], once
    int c = t>>2, q4 = t&3;
    const u16* gp = wot + (size_t)c*128 + q4*32;
    u16* lp = Wt + c*LDW2 + q4*32;
    #pragma unroll
    for (int i=0;i<4;i++) ((uint4*)lp)[i] = ((const uint4*)gp)[i];
  }
  #pragma unroll
  for (int step=0; step<2; ++step) {
    { // write At from regs: pair-transpose + swizzle (cols 2hh2, 2hh2+1)
      u32 w0[4] = {aR0.x,aR0.y,aR0.z,aR0.w};
      u32 w1[4] = {aR1.x,aR1.y,aR1.z,aR1.w};
      u32 sw = (u32)(seg>>1) << 4;
      char* abytes = (char*)At;
      #pragma unroll
      for (int e=0;e<4;e++) {
        u32 lo = w0[e], hi = w1[e];
        u32 evenw = (lo & 0xffffu) | (hi << 16);
        u32 oddw  = (lo >> 16)     | (hi & 0xffff0000u);
        int je = seg*8 + 2*e;
        *(u32*)(abytes + (((u32)(je*LDW + 2*hh2) * 2u) ^ sw)) = evenw;
        *(u32*)(abytes + (((u32)((je+1)*LDW + 2*hh2) * 2u) ^ sw)) = oddw;
      }
    }
    if (step == 0) { // T14: prefetch A(c0=64) during step 0's MFMA
      const u16* g0 = og_ + ((size_t)bx*128 + 64 + 2*hh2)*128 + seg*8;
      aR0 = ((const uint4*)g0)[0];
      aR1 = ((const uint4*)(g0 + 128))[0];
    }
    __syncthreads();
    int c0 = step*64;
    #pragma unroll
    for (int ks=0; ks<2; ks++) {
      int kel = ks*32 + q*8;
      bf16x8_t a = *(const bf16x8_t*)((const char*)At +
                     ((u32)(((m0+nl)*LDW + kel)*2) ^ ((u32)w << 4)));
      bf16x8_t b[8];
      #pragma unroll
      for (int tn=0;tn<8;tn++) b[tn] = *(const bf16x8_t*)(Wt + (tn*16+nl)*LDW2 + c0 + kel);
      #pragma unroll
      for (int tn=0;tn<8;tn++)
        acc[tn] = __builtin_amdgcn_mfma_f32_16x16x32_bf16(a, b[tn], acc[tn], 0,0,0);
    }
    __syncthreads();
  }
  // epilogue: residual + bias, transpose-free rowwise LN via 16-lane shfl reduction
  float rsum[4], rsq[4];
  #pragma unroll
  for (int p=0;p<4;p++) { rsum[p]=0.f; rsq[p]=0.f; }
  #pragma unroll
  for (int tn=0;tn<8;tn++) {
    int n = tn*16 + nl;
    float bb = bo[n];
    #pragma unroll
    for (int p=0;p<4;p++) {
      int m = m0 + q*4 + p;
      float v = acc[tn][p] + bb + pair[(size_t)(r0+m)*128 + n];
      acc[tn][p] = v;
      rsum[p] += v;
      rsq[p]  += v*v;
    }
  }
  #pragma unroll
  for (int msk=1; msk<16; msk<<=1) {
    #pragma unroll
    for (int p=0;p<4;p++) {
      rsum[p] += __shfl_xor(rsum[p], msk, 64);
      rsq[p]  += __shfl_xor(rsq[p],  msk, 64);
    }
  }
  #pragma unroll
  for (int p=0;p<4;p++) {
    float mu = rsum[p] * (1.f/128.f);
    float var = rsq[p]*(1.f/128.f) - mu*mu;
    rsum[p] = mu;
    rsq[p] = rsqrtf(var + 1e-5f);
  }
  #pragma unroll
  for (int tn=0;tn<8;tn++) {
    int n = tn*16 + nl;
    float g = ng[n], b2 = nb_[n];
    #pragma unroll
    for (int p=0;p<4;p++) {
      int m = m0 + q*4 + p;
      out[(size_t)(r0+m)*128 + n] = (acc[tn][p] - rsum[p]) * rsq[p] * g + b2;
    }
  }
}

extern "C" void kernel_launch(void* const* d_in, const int* in_sizes, int n_in,
                              void* d_out, int out_size, void* d_ws, size_t ws_size,
                              hipStream_t stream) {
  (void)in_sizes; (void)n_in; (void)out_size; (void)ws_size;
  const float* pair   = (const float*)d_in[0];
  const float* ln_l_g = (const float*)d_in[1];
  const float* ln_l_b = (const float*)d_in[2];
  const float* ln_r_g = (const float*)d_in[3];
  const float* ln_r_b = (const float*)d_in[4];
  const float* Wl = (const float*)d_in[5];
  const float* bl = (const float*)d_in[6];
  const float* Wr = (const float*)d_in[7];
  const float* br = (const float*)d_in[8];
  const float* Wg = (const float*)d_in[9];
  const float* bg = (const float*)d_in[10];
  const float* Wo = (const float*)d_in[11];
  const float* bo = (const float*)d_in[12];
  const float* n_g = (const float*)d_in[13];
  const float* n_b = (const float*)d_in[14];

  char* ws = (char*)d_ws;
  const size_t SZ = (size_t)M_*128*sizeof(u16);         // 37,748,736 B
  u16*  og    = (u16*)(ws);                             // [1152][128][128]
  u16*  gate  = (u16*)(ws + SZ);                        // [1152][128][128]
  u16*  wcat  = (u16*)(ws + 2*SZ);
  float* bcat = (float*)(ws + 2*SZ + 98304);
  float* csum = (float*)(ws + 2*SZ + 98304 + 1536);     // 256 floats
  u16*  wot   = (u16*)(ws + 2*SZ + 98304 + 1536 + 1024);

  // lr[1152][256][128] (left|right cat) lives in d_out (exactly M_*128*4 B),
  // consumed by k_einsum before k_final overwrites d_out with the fp32 result.
  u16* lr = (u16*)d_out;

  k_prep<<<258, 256, 0, stream>>>(ln_l_g, ln_r_g, Wl, Wr, Wg, Wo,
                                  ln_l_b, ln_r_b, bl, br, bg, wcat, wot, bcat, csum);
  k_projln<<<1152, 256, 0, stream>>>(pair, wcat, bcat, csum, lr, gate);
  k_einsum<<<1152, 512, 0, stream>>>(lr, gate, og);
  k_final<<<1152, 512, 0, stream>>>(og, wot, pair, bo, n_g, n_b, (float*)d_out);
}

// Round 12
// 261.934 us; speedup vs baseline: 1.0579x; 1.0579x over previous
//
#include <hip/hip_runtime.h>
#include <hip/hip_bf16.h>

#define N_ 384
#define C_ 128
#define M_ (N_*N_)   // 147456 rows (i*384+j)

typedef __attribute__((ext_vector_type(8))) short bf16x8_t;
typedef __attribute__((ext_vector_type(4))) float f32x4_t;
typedef unsigned int u32;
typedef unsigned short u16;
typedef unsigned long long u64;

__device__ __forceinline__ u16 f2bf(float f) {
  u32 u = __builtin_bit_cast(u32, f);
  u32 r = (u + 0x7FFFu + ((u >> 16) & 1u)) >> 16;
  return (u16)r;
}
__device__ __forceinline__ float bf2f(u16 h) {
  u32 u = ((u32)h) << 16;
  return __builtin_bit_cast(float, u);
}
// RNE pack of 2 f32 -> 2 bf16 via the NATIVE intrinsic (m240: compiler emits
// v_cvt_pk_bf16_f32 itself with free regalloc; inline asm pinned VGPRs and
// halved occupancy in round 10). Layout: lo in [15:0], hi in [31:16].
// (__hip_bfloat162 is not trivially copyable -> memcpy, which folds to a no-op.)
__device__ __forceinline__ u32 pk2bf(float lo, float hi) {
  __hip_bfloat162 h2 = __float22bfloat162_rn(float2{lo, hi});
  u32 r;
  __builtin_memcpy(&r, &h2, sizeof(r));
  return r;
}

// ---------------- fused prep kernel ----------------
__global__ __launch_bounds__(256) void k_prep(const float* __restrict__ lg, const float* __restrict__ rg,
    const float* __restrict__ Wl, const float* __restrict__ Wr, const float* __restrict__ Wg,
    const float* __restrict__ Wo,
    const float* __restrict__ lb, const float* __restrict__ rb,
    const float* __restrict__ bl, const float* __restrict__ br, const float* __restrict__ bg,
    u16* __restrict__ wcat, u16* __restrict__ wot,
    float* __restrict__ bcat, float* __restrict__ csum) {
  int bx = blockIdx.x, t = threadIdx.x;
  if (bx < 256) {
    int idx = bx*256 + t;
    if (idx < 49152) {
      int n = idx >> 7, k = idx & 127;
      float v;
      if (n < 128)      v = lg[k] * Wl[k*128 + n];
      else if (n < 256) v = rg[k] * Wr[k*128 + (n-128)];
      else              v = Wg[k*128 + (n-256)];
      wcat[idx] = f2bf(v);
    } else {
      int i2 = idx - 49152;           // < 16384
      int c = i2 >> 7, h = i2 & 127;
      wot[i2] = f2bf(Wo[h*128 + c]);
    }
  } else if (bx == 256) {
    float s = 0.f;
    if (t < 128)      { for (int k=0;k<128;k++) s += lb[k]*Wl[k*128+t];       s += bl[t];     bcat[t] = s; }
    else              { int hh=t-128; for (int k=0;k<128;k++) s += rb[k]*Wr[k*128+hh]; s += br[hh]; bcat[t] = s; }
  } else { // bx == 257
    if (t < 128) bcat[256+t] = bg[t];
    float s = 0.f;
    if (t < 128) {
      for (int k=0;k<128;k++) s += bf2f(f2bf(lg[k]*Wl[k*128+t]));
      csum[t] = s;
    } else {
      int hh = t-128;
      for (int k=0;k<128;k++) s += bf2f(f2bf(rg[k]*Wr[k*128+hh]));
      csum[128+hh] = s;
    }
  }
}

#define LDK 136  // u16 stride of staged 128-k rows
#define LDA 72
#define LDW 72
#define LDW2 136
#define LDT 136

// ---------------- K1: LN-folded proj, 256 threads / 4 waves (round-9 structure) ----------------
// Pack-pair sites use __float22bfloat162_rn (compiler-folded v_cvt_pk_bf16_f32,
// no asm operand pinning). Everything else identical to round 9 (76.5us, VGPR 124).
__global__ __launch_bounds__(256) void k_projln(const float* __restrict__ pair,
    const u16* __restrict__ wcat, const float* __restrict__ bcat, const float* __restrict__ csum,
    u16* __restrict__ lr_, u16* __restrict__ gate_) {
  __shared__ u16 At[128*LDK];   // 34816 B
  __shared__ float mu_s[128];
  __shared__ float rstd_s[128];
  int bx = blockIdx.x;
  int t = threadIdx.x, w = t>>6, lane = t&63;
  int q = lane>>4, nl = lane&15;
  int r0 = bx * 128;

  // ---- load + raw-stage + moments: 4 thr/row, 2 passes of 64 rows ----
  #pragma unroll
  for (int pass=0; pass<2; ++pass) {
    int rr = pass*64 + (t>>2), quarter = t&3;
    const float4* gp = (const float4*)(pair + (size_t)(r0+rr)*128 + quarter*32);
    u32* lp = (u32*)(At + rr*LDK + quarter*32);
    float s = 0.f, qq = 0.f;
    #pragma unroll
    for (int i=0;i<4;i++) {
      float4 a = gp[2*i];
      float4 b = gp[2*i+1];
      s  += a.x + a.y + a.z + a.w + b.x + b.y + b.z + b.w;
      qq += a.x*a.x + a.y*a.y + a.z*a.z + a.w*a.w
          + b.x*b.x + b.y*b.y + b.z*b.z + b.w*b.w;
      u32 p0 = pk2bf(a.x, a.y);
      u32 p1 = pk2bf(a.z, a.w);
      u32 p2 = pk2bf(b.x, b.y);
      u32 p3 = pk2bf(b.z, b.w);
      ((uint4*)lp)[i] = make_uint4(p0,p1,p2,p3);
    }
    s  += __shfl_xor(s, 1, 64);
    s  += __shfl_xor(s, 2, 64);
    qq += __shfl_xor(qq, 1, 64);
    qq += __shfl_xor(qq, 2, 64);
    if (quarter == 0) {
      float mu = s * (1.f/128.f);
      float var = qq*(1.f/128.f) - mu*mu;
      mu_s[rr] = mu;
      rstd_s[rr] = rsqrtf(var + 1e-5f);
    }
  }
  __syncthreads();

  #pragma unroll 1
  for (int nb = 0; nb < 3; ++nb) {
    #pragma unroll 1
    for (int nh = 0; nh < 2; ++nh) {
      int n = nh*64 + w*16 + nl;
      const u16* brow = wcat + (size_t)(nb*128 + n)*128;
      f32x4_t acc[8] = {};   // [tm] ; m = tm*16+q*4+p
      #pragma unroll
      for (int ks=0; ks<4; ks++) {
        int kel = ks*32 + q*8;
        bf16x8_t b = *(const bf16x8_t*)(brow + kel);
        #pragma unroll
        for (int tm=0;tm<8;tm++) {
          bf16x8_t a = *(const bf16x8_t*)(At + (tm*16+nl)*LDK + kel);
          acc[tm] = __builtin_amdgcn_mfma_f32_16x16x32_bf16(a, b, acc[tm], 0,0,0);
        }
      }
      float bias = bcat[nb*128 + n];
      u16* rowp;
      if (nb == 0)      rowp = lr_   + ((size_t)bx*256 + n)*128;
      else if (nb == 1) rowp = lr_   + ((size_t)bx*256 + 128 + n)*128;
      else              rowp = gate_ + ((size_t)bx*128 + n)*128;
      if (nb == 2) {
        #pragma unroll
        for (int tm=0;tm<8;tm++) {
          float v0 = acc[tm][0] + bias;
          float v1 = acc[tm][1] + bias;
          float v2 = acc[tm][2] + bias;
          float v3 = acc[tm][3] + bias;
          v0 = 1.0f/(1.0f+__expf(-v0));
          v1 = 1.0f/(1.0f+__expf(-v1));
          v2 = 1.0f/(1.0f+__expf(-v2));
          v3 = 1.0f/(1.0f+__expf(-v3));
          u32 pk0 = pk2bf(v0, v1);
          u32 pk1 = pk2bf(v2, v3);
          *(u64*)(rowp + tm*16 + q*4) = (u64)pk0 | ((u64)pk1<<32);
        }
      } else {
        float csn = csum[nb*128 + n];
        #pragma unroll
        for (int tm=0;tm<8;tm++) {
          f32x4_t mu4 = *(const f32x4_t*)(mu_s   + tm*16 + q*4);
          f32x4_t rs4 = *(const f32x4_t*)(rstd_s + tm*16 + q*4);
          float v0 = (acc[tm][0] - mu4[0]*csn)*rs4[0] + bias;
          float v1 = (acc[tm][1] - mu4[1]*csn)*rs4[1] + bias;
          float v2 = (acc[tm][2] - mu4[2]*csn)*rs4[2] + bias;
          float v3 = (acc[tm][3] - mu4[3]*csn)*rs4[3] + bias;
          u32 pk0 = pk2bf(v0, v1);
          u32 pk1 = pk2bf(v2, v3);
          *(u64*)(rowp + tm*16 + q*4) = (u64)pk0 | ((u64)pk1<<32);
        }
      }
    }
  }
}

// ---------------- K2: triangle einsum per h + gate multiply ----------------
// Round-9 structure; gate-multiply store uses the native pk2bf.
__global__ __launch_bounds__(512) void k_einsum(const u16* __restrict__ lr_,
    const u16* __restrict__ gate_, u16* __restrict__ og_) {
  __shared__ u16 smem[2*128*LDA];  // 36864 B
  u16* At = smem; u16* Bt = smem + 128*LDA;
  int bx = blockIdx.x;
  int wk = (bx & 7) * 144 + (bx >> 3);   // XCD-chunked bijection on 1152
  int h = wk / 9; int rem = wk % 9;
  int i0 = (rem/3)*128, j0c = rem%3;     // j0 = j0c*128
  int t = threadIdx.x, w = t>>6, lane = t&63;
  int q = lane>>4, nl = lane&15;
  f32x4_t acc[4][2] = {};
  int m0 = (w&1)*64, nb0 = (w>>1)*32;

  int rrA = t>>2, quarterA = t&3;        // A staging ids
  int kk2 = t>>4, seg = t&15;            // B staging ids

  uint4 aR0, aR1, bR0, bR1;
  { // prologue: loads for step 0 (kb=0 -> c=0, off=0)
    const u16* ga = lr_ + (((size_t)(i0+rrA)*3 + 0)*256 + h)*128 + quarterA*16;
    aR0 = ((const uint4*)ga)[0]; aR1 = ((const uint4*)ga)[1];
    const u16* g0 = lr_ + (((size_t)(2*kk2)*3 + j0c)*256 + 128 + h)*128 + seg*8;
    bR0 = ((const uint4*)g0)[0];
    bR1 = ((const uint4*)(g0 + 3*256*128))[0];
  }
  #pragma unroll 1
  for (int s = 0; s < 6; ++s) {
    { // write A tile from regs
      u16* lp = At + rrA*LDA + quarterA*16;
      ((uint4*)lp)[0] = aR0; ((uint4*)lp)[1] = aR1;
    }
    { // write B tile: register pair-transpose + XOR swizzle
      u32 w0[4] = {bR0.x,bR0.y,bR0.z,bR0.w};
      u32 w1[4] = {bR1.x,bR1.y,bR1.z,bR1.w};
      u32 sw = (u32)(seg>>1) << 4;
      char* bbytes = (char*)Bt;
      #pragma unroll
      for (int e=0;e<4;e++) {
        u32 lo = w0[e], hi = w1[e];
        u32 evenw = (lo & 0xffffu) | (hi << 16);
        u32 oddw  = (lo >> 16)     | (hi & 0xffff0000u);
        int je = seg*8 + 2*e;
        *(u32*)(bbytes + (((u32)(je*LDA + 2*kk2) * 2u) ^ sw)) = evenw;
        *(u32*)(bbytes + (((u32)((je+1)*LDA + 2*kk2) * 2u) ^ sw)) = oddw;
      }
    }
    if (s < 5) { // T14: issue next-step loads NOW (in flight through bar+MFMA+bar)
      int kb = (s+1)*64; int c = kb>>7, off = kb&127;
      const u16* ga = lr_ + (((size_t)(i0+rrA)*3 + c)*256 + h)*128 + off + quarterA*16;
      aR0 = ((const uint4*)ga)[0]; aR1 = ((const uint4*)ga)[1];
      const u16* g0 = lr_ + (((size_t)(kb + 2*kk2)*3 + j0c)*256 + 128 + h)*128 + seg*8;
      bR0 = ((const uint4*)g0)[0];
      bR1 = ((const uint4*)(g0 + 3*256*128))[0];
    }
    __syncthreads();
    #pragma unroll
    for (int ks=0; ks<2; ks++) {
      int kel = ks*32 + q*8;
      bf16x8_t a[4], b[2];
      #pragma unroll
      for (int tm=0;tm<4;tm++) a[tm] = *(const bf16x8_t*)(At + (m0+tm*16+nl)*LDA + kel);
      #pragma unroll
      for (int tn=0;tn<2;tn++) {
        u32 swr = (u32)(((nb0>>4) + tn) & 7) << 4;
        b[tn] = *(const bf16x8_t*)((const char*)Bt + ((u32)(((nb0+tn*16+nl)*LDA + kel)*2) ^ swr));
      }
      #pragma unroll
      for (int tm=0;tm<4;tm++)
        #pragma unroll
        for (int tn=0;tn<2;tn++)
          acc[tm][tn] = __builtin_amdgcn_mfma_f32_16x16x32_bf16(a[tm], b[tn], acc[tm][tn], 0,0,0);
    }
    __syncthreads();
  }
  // epilogue: acc -> LDS bf16 [m][n], then gate-multiplied coalesced store (og[rb][h][j])
  u16* Ot = smem;  // 128*LDT u16 = 34816 B <= 36864
  #pragma unroll
  for (int tm=0;tm<4;tm++)
    #pragma unroll
    for (int tn=0;tn<2;tn++)
      #pragma unroll
      for (int p=0;p<4;p++) {
        int m = m0 + tm*16 + q*4 + p;
        int n = nb0 + tn*16 + nl;
        Ot[m*LDT + n] = f2bf(acc[tm][tn][p]);
      }
  __syncthreads();
  {
    int m = t>>2, hq = t&3;
    size_t gbase = (((size_t)(i0+m)*3 + j0c)*128 + h)*128 + hq*32;
    const uint4* gg = (const uint4*)(gate_ + gbase);
    const uint4* lo = (const uint4*)(Ot + m*LDT + hq*32);
    uint4* od = (uint4*)(og_ + gbase);
    #pragma unroll
    for (int i=0;i<4;i++) {
      uint4 gv = gg[i]; uint4 ov = lo[i];
      u32 ga[4] = {gv.x,gv.y,gv.z,gv.w};
      u32 oa[4] = {ov.x,ov.y,ov.z,ov.w};
      u32 ra2[4];
      #pragma unroll
      for (int e=0;e<4;e++) {
        float g0 = bf2f((u16)(ga[e]&0xffffu)), g1 = bf2f((u16)(ga[e]>>16));
        float o0 = bf2f((u16)(oa[e]&0xffffu)), o1 = bf2f((u16)(oa[e]>>16));
        ra2[e] = pk2bf(o0*g0, o1*g1);
      }
      od[i] = make_uint4(ra2[0],ra2[1],ra2[2],ra2[3]);
    }
  }
}

// ---------------- K3: og @ Wo + bo + pair, rowwise LN, fp32 out (unchanged control) ----------------
__global__ __launch_bounds__(512) void k_final(const u16* __restrict__ og_, const u16* __restrict__ wot,
    const float* __restrict__ pair, const float* __restrict__ bo,
    const float* __restrict__ ng, const float* __restrict__ nb_,
    float* __restrict__ out) {
  __shared__ u16 At[128*LDW];    // 18432 B
  __shared__ u16 Wt[128*LDW2];   // 34816 B
  int bx = blockIdx.x;
  int r0 = bx * 128;
  int t = threadIdx.x, w = t>>6, lane = t&63;
  int q = lane>>4, nl = lane&15;
  f32x4_t acc[8] = {};
  int m0 = w*16;
  int hh2 = t>>4, seg = t&15;    // A staging: column pair 2*hh2, r-chunk seg*8

  uint4 aR0, aR1;
  { // prologue: A(c0=0) loads
    const u16* g0 = og_ + ((size_t)bx*128 + 2*hh2)*128 + seg*8;
    aR0 = ((const uint4*)g0)[0];
    aR1 = ((const uint4*)(g0 + 128))[0];
  }
  { // stage full Wo -> Wt[c][k], once
    int c = t>>2, q4 = t&3;
    const u16* gp = wot + (size_t)c*128 + q4*32;
    u16* lp = Wt + c*LDW2 + q4*32;
    #pragma unroll
    for (int i=0;i<4;i++) ((uint4*)lp)[i] = ((const uint4*)gp)[i];
  }
  #pragma unroll
  for (int step=0; step<2; ++step) {
    { // write At from regs: pair-transpose + swizzle (cols 2hh2, 2hh2+1)
      u32 w0[4] = {aR0.x,aR0.y,aR0.z,aR0.w};
      u32 w1[4] = {aR1.x,aR1.y,aR1.z,aR1.w};
      u32 sw = (u32)(seg>>1) << 4;
      char* abytes = (char*)At;
      #pragma unroll
      for (int e=0;e<4;e++) {
        u32 lo = w0[e], hi = w1[e];
        u32 evenw = (lo & 0xffffu) | (hi << 16);
        u32 oddw  = (lo >> 16)     | (hi & 0xffff0000u);
        int je = seg*8 + 2*e;
        *(u32*)(abytes + (((u32)(je*LDW + 2*hh2) * 2u) ^ sw)) = evenw;
        *(u32*)(abytes + (((u32)((je+1)*LDW + 2*hh2) * 2u) ^ sw)) = oddw;
      }
    }
    if (step == 0) { // T14: prefetch A(c0=64) during step 0's MFMA
      const u16* g0 = og_ + ((size_t)bx*128 + 64 + 2*hh2)*128 + seg*8;
      aR0 = ((const uint4*)g0)[0];
      aR1 = ((const uint4*)(g0 + 128))[0];
    }
    __syncthreads();
    int c0 = step*64;
    #pragma unroll
    for (int ks=0; ks<2; ks++) {
      int kel = ks*32 + q*8;
      bf16x8_t a = *(const bf16x8_t*)((const char*)At +
                     ((u32)(((m0+nl)*LDW + kel)*2) ^ ((u32)w << 4)));
      bf16x8_t b[8];
      #pragma unroll
      for (int tn=0;tn<8;tn++) b[tn] = *(const bf16x8_t*)(Wt + (tn*16+nl)*LDW2 + c0 + kel);
      #pragma unroll
      for (int tn=0;tn<8;tn++)
        acc[tn] = __builtin_amdgcn_mfma_f32_16x16x32_bf16(a, b[tn], acc[tn], 0,0,0);
    }
    __syncthreads();
  }
  // epilogue: residual + bias, transpose-free rowwise LN via 16-lane shfl reduction
  float rsum[4], rsq[4];
  #pragma unroll
  for (int p=0;p<4;p++) { rsum[p]=0.f; rsq[p]=0.f; }
  #pragma unroll
  for (int tn=0;tn<8;tn++) {
    int n = tn*16 + nl;
    float bb = bo[n];
    #pragma unroll
    for (int p=0;p<4;p++) {
      int m = m0 + q*4 + p;
      float v = acc[tn][p] + bb + pair[(size_t)(r0+m)*128 + n];
      acc[tn][p] = v;
      rsum[p] += v;
      rsq[p]  += v*v;
    }
  }
  #pragma unroll
  for (int msk=1; msk<16; msk<<=1) {
    #pragma unroll
    for (int p=0;p<4;p++) {
      rsum[p] += __shfl_xor(rsum[p], msk, 64);
      rsq[p]  += __shfl_xor(rsq[p],  msk, 64);
    }
  }
  #pragma unroll
  for (int p=0;p<4;p++) {
    float mu = rsum[p] * (1.f/128.f);
    float var = rsq[p]*(1.f/128.f) - mu*mu;
    rsum[p] = mu;
    rsq[p] = rsqrtf(var + 1e-5f);
  }
  #pragma unroll
  for (int tn=0;tn<8;tn++) {
    int n = tn*16 + nl;
    float g = ng[n], b2 = nb_[n];
    #pragma unroll
    for (int p=0;p<4;p++) {
      int m = m0 + q*4 + p;
      out[(size_t)(r0+m)*128 + n] = (acc[tn][p] - rsum[p]) * rsq[p] * g + b2;
    }
  }
}

extern "C" void kernel_launch(void* const* d_in, const int* in_sizes, int n_in,
                              void* d_out, int out_size, void* d_ws, size_t ws_size,
                              hipStream_t stream) {
  (void)in_sizes; (void)n_in; (void)out_size; (void)ws_size;
  const float* pair   = (const float*)d_in[0];
  const float* ln_l_g = (const float*)d_in[1];
  const float* ln_l_b = (const float*)d_in[2];
  const float* ln_r_g = (const float*)d_in[3];
  const float* ln_r_b = (const float*)d_in[4];
  const float* Wl = (const float*)d_in[5];
  const float* bl = (const float*)d_in[6];
  const float* Wr = (const float*)d_in[7];
  const float* br = (const float*)d_in[8];
  const float* Wg = (const float*)d_in[9];
  const float* bg = (const float*)d_in[10];
  const float* Wo = (const float*)d_in[11];
  const float* bo = (const float*)d_in[12];
  const float* n_g = (const float*)d_in[13];
  const float* n_b = (const float*)d_in[14];

  char* ws = (char*)d_ws;
  const size_t SZ = (size_t)M_*128*sizeof(u16);         // 37,748,736 B
  u16*  og    = (u16*)(ws);                             // [1152][128][128]
  u16*  gate  = (u16*)(ws + SZ);                        // [1152][128][128]
  u16*  wcat  = (u16*)(ws + 2*SZ);
  float* bcat = (float*)(ws + 2*SZ + 98304);
  float* csum = (float*)(ws + 2*SZ + 98304 + 1536);     // 256 floats
  u16*  wot   = (u16*)(ws + 2*SZ + 98304 + 1536 + 1024);

  // lr[1152][256][128] (left|right cat) lives in d_out (exactly M_*128*4 B),
  // consumed by k_einsum before k_final overwrites d_out with the fp32 result.
  u16* lr = (u16*)d_out;

  k_prep<<<258, 256, 0, stream>>>(ln_l_g, ln_r_g, Wl, Wr, Wg, Wo,
                                  ln_l_b, ln_r_b, bl, br, bg, wcat, wot, bcat, csum);
  k_projln<<<1152, 256, 0, stream>>>(pair, wcat, bcat, csum, lr, gate);
  k_einsum<<<1152, 512, 0, stream>>>(lr, gate, og);
  k_final<<<1152, 512, 0, stream>>>(og, wot, pair, bo, n_g, n_b, (float*)d_out);
}

// Round 13
// 260.579 us; speedup vs baseline: 1.0634x; 1.0052x over previous
//
#include <hip/hip_runtime.h>
#include <hip/hip_bf16.h>

#define N_ 384
#define C_ 128
#define M_ (N_*N_)   // 147456 rows (i*384+j)

typedef __attribute__((ext_vector_type(8))) short bf16x8_t;
typedef __attribute__((ext_vector_type(4))) float f32x4_t;
typedef unsigned int u32;
typedef unsigned short u16;
typedef unsigned long long u64;

__device__ __forceinline__ u16 f2bf(float f) {
  u32 u = __builtin_bit_cast(u32, f);
  u32 r = (u + 0x7FFFu + ((u >> 16) & 1u)) >> 16;
  return (u16)r;
}
__device__ __forceinline__ float bf2f(u16 h) {
  u32 u = ((u32)h) << 16;
  return __builtin_bit_cast(float, u);
}
// Native RNE pair-pack (kept ONLY in einsum's epilogue where round 12 showed a
// gain; round 12 also showed it REGRESSES projln's LN loop, so projln uses f2bf).
__device__ __forceinline__ u32 pk2bf(float lo, float hi) {
  __hip_bfloat162 h2 = __float22bfloat162_rn(float2{lo, hi});
  u32 r;
  __builtin_memcpy(&r, &h2, sizeof(r));
  return r;
}

// ---------------- fused prep kernel ----------------
__global__ __launch_bounds__(256) void k_prep(const float* __restrict__ lg, const float* __restrict__ rg,
    const float* __restrict__ Wl, const float* __restrict__ Wr, const float* __restrict__ Wg,
    const float* __restrict__ Wo,
    const float* __restrict__ lb, const float* __restrict__ rb,
    const float* __restrict__ bl, const float* __restrict__ br, const float* __restrict__ bg,
    u16* __restrict__ wcat, u16* __restrict__ wot,
    float* __restrict__ bcat, float* __restrict__ csum) {
  int bx = blockIdx.x, t = threadIdx.x;
  if (bx < 256) {
    int idx = bx*256 + t;
    if (idx < 49152) {
      int n = idx >> 7, k = idx & 127;
      float v;
      if (n < 128)      v = lg[k] * Wl[k*128 + n];
      else if (n < 256) v = rg[k] * Wr[k*128 + (n-128)];
      else              v = Wg[k*128 + (n-256)];
      wcat[idx] = f2bf(v);
    } else {
      int i2 = idx - 49152;           // < 16384
      int c = i2 >> 7, h = i2 & 127;
      wot[i2] = f2bf(Wo[h*128 + c]);
    }
  } else if (bx == 256) {
    float s = 0.f;
    if (t < 128)      { for (int k=0;k<128;k++) s += lb[k]*Wl[k*128+t];       s += bl[t];     bcat[t] = s; }
    else              { int hh=t-128; for (int k=0;k<128;k++) s += rb[k]*Wr[k*128+hh]; s += br[hh]; bcat[t] = s; }
  } else { // bx == 257
    if (t < 128) bcat[256+t] = bg[t];
    float s = 0.f;
    if (t < 128) {
      for (int k=0;k<128;k++) s += bf2f(f2bf(lg[k]*Wl[k*128+t]));
      csum[t] = s;
    } else {
      int hh = t-128;
      for (int k=0;k<128;k++) s += bf2f(f2bf(rg[k]*Wr[k*128+hh]));
      csum[128+hh] = s;
    }
  }
}

#define LDK 136  // u16 stride of staged 128-k rows
#define LDA 72
#define LDW 72
#define LDW2 136
#define LDT 136

// ---------------- K1: LN-folded proj, 256 threads / 4 waves (EXACT round-9 version, 76.5us) ----------------
__global__ __launch_bounds__(256) void k_projln(const float* __restrict__ pair,
    const u16* __restrict__ wcat, const float* __restrict__ bcat, const float* __restrict__ csum,
    u16* __restrict__ lr_, u16* __restrict__ gate_) {
  __shared__ u16 At[128*LDK];   // 34816 B
  __shared__ float mu_s[128];
  __shared__ float rstd_s[128];
  int bx = blockIdx.x;
  int t = threadIdx.x, w = t>>6, lane = t&63;
  int q = lane>>4, nl = lane&15;
  int r0 = bx * 128;

  // ---- load + raw-stage + moments: 4 thr/row, 2 passes of 64 rows ----
  #pragma unroll
  for (int pass=0; pass<2; ++pass) {
    int rr = pass*64 + (t>>2), quarter = t&3;
    const float4* gp = (const float4*)(pair + (size_t)(r0+rr)*128 + quarter*32);
    u32* lp = (u32*)(At + rr*LDK + quarter*32);
    float s = 0.f, qq = 0.f;
    #pragma unroll
    for (int i=0;i<4;i++) {
      float4 a = gp[2*i];
      float4 b = gp[2*i+1];
      s  += a.x + a.y + a.z + a.w + b.x + b.y + b.z + b.w;
      qq += a.x*a.x + a.y*a.y + a.z*a.z + a.w*a.w
          + b.x*b.x + b.y*b.y + b.z*b.z + b.w*b.w;
      u32 p0 = (u32)f2bf(a.x) | ((u32)f2bf(a.y)<<16);
      u32 p1 = (u32)f2bf(a.z) | ((u32)f2bf(a.w)<<16);
      u32 p2 = (u32)f2bf(b.x) | ((u32)f2bf(b.y)<<16);
      u32 p3 = (u32)f2bf(b.z) | ((u32)f2bf(b.w)<<16);
      ((uint4*)lp)[i] = make_uint4(p0,p1,p2,p3);
    }
    s  += __shfl_xor(s, 1, 64);
    s  += __shfl_xor(s, 2, 64);
    qq += __shfl_xor(qq, 1, 64);
    qq += __shfl_xor(qq, 2, 64);
    if (quarter == 0) {
      float mu = s * (1.f/128.f);
      float var = qq*(1.f/128.f) - mu*mu;
      mu_s[rr] = mu;
      rstd_s[rr] = rsqrtf(var + 1e-5f);
    }
  }
  __syncthreads();

  #pragma unroll 1
  for (int nb = 0; nb < 3; ++nb) {
    #pragma unroll 1
    for (int nh = 0; nh < 2; ++nh) {
      int n = nh*64 + w*16 + nl;
      const u16* brow = wcat + (size_t)(nb*128 + n)*128;
      f32x4_t acc[8] = {};   // [tm] ; m = tm*16+q*4+p
      #pragma unroll
      for (int ks=0; ks<4; ks++) {
        int kel = ks*32 + q*8;
        bf16x8_t b = *(const bf16x8_t*)(brow + kel);
        #pragma unroll
        for (int tm=0;tm<8;tm++) {
          bf16x8_t a = *(const bf16x8_t*)(At + (tm*16+nl)*LDK + kel);
          acc[tm] = __builtin_amdgcn_mfma_f32_16x16x32_bf16(a, b, acc[tm], 0,0,0);
        }
      }
      float bias = bcat[nb*128 + n];
      u16* rowp;
      if (nb == 0)      rowp = lr_   + ((size_t)bx*256 + n)*128;
      else if (nb == 1) rowp = lr_   + ((size_t)bx*256 + 128 + n)*128;
      else              rowp = gate_ + ((size_t)bx*128 + n)*128;
      if (nb == 2) {
        #pragma unroll
        for (int tm=0;tm<8;tm++) {
          float v0 = acc[tm][0] + bias;
          float v1 = acc[tm][1] + bias;
          float v2 = acc[tm][2] + bias;
          float v3 = acc[tm][3] + bias;
          v0 = 1.0f/(1.0f+__expf(-v0));
          v1 = 1.0f/(1.0f+__expf(-v1));
          v2 = 1.0f/(1.0f+__expf(-v2));
          v3 = 1.0f/(1.0f+__expf(-v3));
          u32 pk0 = (u32)f2bf(v0) | ((u32)f2bf(v1)<<16);
          u32 pk1 = (u32)f2bf(v2) | ((u32)f2bf(v3)<<16);
          *(u64*)(rowp + tm*16 + q*4) = (u64)pk0 | ((u64)pk1<<32);
        }
      } else {
        float csn = csum[nb*128 + n];
        #pragma unroll
        for (int tm=0;tm<8;tm++) {
          f32x4_t mu4 = *(const f32x4_t*)(mu_s   + tm*16 + q*4);
          f32x4_t rs4 = *(const f32x4_t*)(rstd_s + tm*16 + q*4);
          float v0 = (acc[tm][0] - mu4[0]*csn)*rs4[0] + bias;
          float v1 = (acc[tm][1] - mu4[1]*csn)*rs4[1] + bias;
          float v2 = (acc[tm][2] - mu4[2]*csn)*rs4[2] + bias;
          float v3 = (acc[tm][3] - mu4[3]*csn)*rs4[3] + bias;
          u32 pk0 = (u32)f2bf(v0) | ((u32)f2bf(v1)<<16);
          u32 pk1 = (u32)f2bf(v2) | ((u32)f2bf(v3)<<16);
          *(u64*)(rowp + tm*16 + q*4) = (u64)pk0 | ((u64)pk1<<32);
        }
      }
    }
  }
}

// ---------------- K2: triangle einsum per h + gate multiply (round-12 version, pk2bf epilogue) ----------------
__global__ __launch_bounds__(512) void k_einsum(const u16* __restrict__ lr_,
    const u16* __restrict__ gate_, u16* __restrict__ og_) {
  __shared__ u16 smem[2*128*LDA];  // 36864 B
  u16* At = smem; u16* Bt = smem + 128*LDA;
  int bx = blockIdx.x;
  int wk = (bx & 7) * 144 + (bx >> 3);   // XCD-chunked bijection on 1152
  int h = wk / 9; int rem = wk % 9;
  int i0 = (rem/3)*128, j0c = rem%3;     // j0 = j0c*128
  int t = threadIdx.x, w = t>>6, lane = t&63;
  int q = lane>>4, nl = lane&15;
  f32x4_t acc[4][2] = {};
  int m0 = (w&1)*64, nb0 = (w>>1)*32;

  int rrA = t>>2, quarterA = t&3;        // A staging ids
  int kk2 = t>>4, seg = t&15;            // B staging ids

  uint4 aR0, aR1, bR0, bR1;
  { // prologue: loads for step 0 (kb=0 -> c=0, off=0)
    const u16* ga = lr_ + (((size_t)(i0+rrA)*3 + 0)*256 + h)*128 + quarterA*16;
    aR0 = ((const uint4*)ga)[0]; aR1 = ((const uint4*)ga)[1];
    const u16* g0 = lr_ + (((size_t)(2*kk2)*3 + j0c)*256 + 128 + h)*128 + seg*8;
    bR0 = ((const uint4*)g0)[0];
    bR1 = ((const uint4*)(g0 + 3*256*128))[0];
  }
  #pragma unroll 1
  for (int s = 0; s < 6; ++s) {
    { // write A tile from regs
      u16* lp = At + rrA*LDA + quarterA*16;
      ((uint4*)lp)[0] = aR0; ((uint4*)lp)[1] = aR1;
    }
    { // write B tile: register pair-transpose + XOR swizzle
      u32 w0[4] = {bR0.x,bR0.y,bR0.z,bR0.w};
      u32 w1[4] = {bR1.x,bR1.y,bR1.z,bR1.w};
      u32 sw = (u32)(seg>>1) << 4;
      char* bbytes = (char*)Bt;
      #pragma unroll
      for (int e=0;e<4;e++) {
        u32 lo = w0[e], hi = w1[e];
        u32 evenw = (lo & 0xffffu) | (hi << 16);
        u32 oddw  = (lo >> 16)     | (hi & 0xffff0000u);
        int je = seg*8 + 2*e;
        *(u32*)(bbytes + (((u32)(je*LDA + 2*kk2) * 2u) ^ sw)) = evenw;
        *(u32*)(bbytes + (((u32)((je+1)*LDA + 2*kk2) * 2u) ^ sw)) = oddw;
      }
    }
    if (s < 5) { // T14: issue next-step loads NOW (in flight through bar+MFMA+bar)
      int kb = (s+1)*64; int c = kb>>7, off = kb&127;
      const u16* ga = lr_ + (((size_t)(i0+rrA)*3 + c)*256 + h)*128 + off + quarterA*16;
      aR0 = ((const uint4*)ga)[0]; aR1 = ((const uint4*)ga)[1];
      const u16* g0 = lr_ + (((size_t)(kb + 2*kk2)*3 + j0c)*256 + 128 + h)*128 + seg*8;
      bR0 = ((const uint4*)g0)[0];
      bR1 = ((const uint4*)(g0 + 3*256*128))[0];
    }
    __syncthreads();
    #pragma unroll
    for (int ks=0; ks<2; ks++) {
      int kel = ks*32 + q*8;
      bf16x8_t a[4], b[2];
      #pragma unroll
      for (int tm=0;tm<4;tm++) a[tm] = *(const bf16x8_t*)(At + (m0+tm*16+nl)*LDA + kel);
      #pragma unroll
      for (int tn=0;tn<2;tn++) {
        u32 swr = (u32)(((nb0>>4) + tn) & 7) << 4;
        b[tn] = *(const bf16x8_t*)((const char*)Bt + ((u32)(((nb0+tn*16+nl)*LDA + kel)*2) ^ swr));
      }
      #pragma unroll
      for (int tm=0;tm<4;tm++)
        #pragma unroll
        for (int tn=0;tn<2;tn++)
          acc[tm][tn] = __builtin_amdgcn_mfma_f32_16x16x32_bf16(a[tm], b[tn], acc[tm][tn], 0,0,0);
    }
    __syncthreads();
  }
  // epilogue: acc -> LDS bf16 [m][n], then gate-multiplied coalesced store (og[rb][h][j])
  u16* Ot = smem;  // 128*LDT u16 = 34816 B <= 36864
  #pragma unroll
  for (int tm=0;tm<4;tm++)
    #pragma unroll
    for (int tn=0;tn<2;tn++)
      #pragma unroll
      for (int p=0;p<4;p++) {
        int m = m0 + tm*16 + q*4 + p;
        int n = nb0 + tn*16 + nl;
        Ot[m*LDT + n] = f2bf(acc[tm][tn][p]);
      }
  __syncthreads();
  {
    int m = t>>2, hq = t&3;
    size_t gbase = (((size_t)(i0+m)*3 + j0c)*128 + h)*128 + hq*32;
    const uint4* gg = (const uint4*)(gate_ + gbase);
    const uint4* lo = (const uint4*)(Ot + m*LDT + hq*32);
    uint4* od = (uint4*)(og_ + gbase);
    #pragma unroll
    for (int i=0;i<4;i++) {
      uint4 gv = gg[i]; uint4 ov = lo[i];
      u32 ga[4] = {gv.x,gv.y,gv.z,gv.w};
      u32 oa[4] = {ov.x,ov.y,ov.z,ov.w};
      u32 ra2[4];
      #pragma unroll
      for (int e=0;e<4;e++) {
        float g0 = bf2f((u16)(ga[e]&0xffffu)), g1 = bf2f((u16)(ga[e]>>16));
        float o0 = bf2f((u16)(oa[e]&0xffffu)), o1 = bf2f((u16)(oa[e]>>16));
        ra2[e] = pk2bf(o0*g0, o1*g1);
      }
      od[i] = make_uint4(ra2[0],ra2[1],ra2[2],ra2[3]);
    }
  }
}

// ---------------- K3: og @ Wo + bo + pair, rowwise LN, fp32 out (unchanged control) ----------------
__global__ __launch_bounds__(512) void k_final(const u16* __restrict__ og_, const u16* __restrict__ wot,
    const float* __restrict__ pair, const float* __restrict__ bo,
    const float* __restrict__ ng, const float* __restrict__ nb_,
    float* __restrict__ out) {
  __shared__ u16 At[128*LDW];    // 18432 B
  __shared__ u16 Wt[128*LDW2];   // 34816 B
  int bx = blockIdx.x;
  int r0 = bx * 128;
  int t = threadIdx.x, w = t>>6, lane = t&63;
  int q = lane>>4, nl = lane&15;
  f32x4_t acc[8] = {};
  int m0 = w*16;
  int hh2 = t>>4, seg = t&15;    // A staging: column pair 2*hh2, r-chunk seg*8

  uint4 aR0, aR1;
  { // prologue: A(c0=0) loads
    const u16* g0 = og_ + ((size_t)bx*128 + 2*hh2)*128 + seg*8;
    aR0 = ((const uint4*)g0)[0];
    aR1 = ((const uint4*)(g0 + 128))[0];
  }
  { // stage full Wo -> Wt[c][k], once
    int c = t>>2, q4 = t&3;
    const u16* gp = wot + (size_t)c*128 + q4*32;
    u16* lp = Wt + c*LDW2 + q4*32;
    #pragma unroll
    for (int i=0;i<4;i++) ((uint4*)lp)[i] = ((const uint4*)gp)[i];
  }
  #pragma unroll
  for (int step=0; step<2; ++step) {
    { // write At from regs: pair-transpose + swizzle (cols 2hh2, 2hh2+1)
      u32 w0[4] = {aR0.x,aR0.y,aR0.z,aR0.w};
      u32 w1[4] = {aR1.x,aR1.y,aR1.z,aR1.w};
      u32 sw = (u32)(seg>>1) << 4;
      char* abytes = (char*)At;
      #pragma unroll
      for (int e=0;e<4;e++) {
        u32 lo = w0[e], hi = w1[e];
        u32 evenw = (lo & 0xffffu) | (hi << 16);
        u32 oddw  = (lo >> 16)     | (hi & 0xffff0000u);
        int je = seg*8 + 2*e;
        *(u32*)(abytes + (((u32)(je*LDW + 2*hh2) * 2u) ^ sw)) = evenw;
        *(u32*)(abytes + (((u32)((je+1)*LDW + 2*hh2) * 2u) ^ sw)) = oddw;
      }
    }
    if (step == 0) { // T14: prefetch A(c0=64) during step 0's MFMA
      const u16* g0 = og_ + ((size_t)bx*128 + 64 + 2*hh2)*128 + seg*8;
      aR0 = ((const uint4*)g0)[0];
      aR1 = ((const uint4*)(g0 + 128))[0];
    }
    __syncthreads();
    int c0 = step*64;
    #pragma unroll
    for (int ks=0; ks<2; ks++) {
      int kel = ks*32 + q*8;
      bf16x8_t a = *(const bf16x8_t*)((const char*)At +
                     ((u32)(((m0+nl)*LDW + kel)*2) ^ ((u32)w << 4)));
      bf16x8_t b[8];
      #pragma unroll
      for (int tn=0;tn<8;tn++) b[tn] = *(const bf16x8_t*)(Wt + (tn*16+nl)*LDW2 + c0 + kel);
      #pragma unroll
      for (int tn=0;tn<8;tn++)
        acc[tn] = __builtin_amdgcn_mfma_f32_16x16x32_bf16(a, b[tn], acc[tn], 0,0,0);
    }
    __syncthreads();
  }
  // epilogue: residual + bias, transpose-free rowwise LN via 16-lane shfl reduction
  float rsum[4], rsq[4];
  #pragma unroll
  for (int p=0;p<4;p++) { rsum[p]=0.f; rsq[p]=0.f; }
  #pragma unroll
  for (int tn=0;tn<8;tn++) {
    int n = tn*16 + nl;
    float bb = bo[n];
    #pragma unroll
    for (int p=0;p<4;p++) {
      int m = m0 + q*4 + p;
      float v = acc[tn][p] + bb + pair[(size_t)(r0+m)*128 + n];
      acc[tn][p] = v;
      rsum[p] += v;
      rsq[p]  += v*v;
    }
  }
  #pragma unroll
  for (int msk=1; msk<16; msk<<=1) {
    #pragma unroll
    for (int p=0;p<4;p++) {
      rsum[p] += __shfl_xor(rsum[p], msk, 64);
      rsq[p]  += __shfl_xor(rsq[p],  msk, 64);
    }
  }
  #pragma unroll
  for (int p=0;p<4;p++) {
    float mu = rsum[p] * (1.f/128.f);
    float var = rsq[p]*(1.f/128.f) - mu*mu;
    rsum[p] = mu;
    rsq[p] = rsqrtf(var + 1e-5f);
  }
  #pragma unroll
  for (int tn=0;tn<8;tn++) {
    int n = tn*16 + nl;
    float g = ng[n], b2 = nb_[n];
    #pragma unroll
    for (int p=0;p<4;p++) {
      int m = m0 + q*4 + p;
      out[(size_t)(r0+m)*128 + n] = (acc[tn][p] - rsum[p]) * rsq[p] * g + b2;
    }
  }
}

extern "C" void kernel_launch(void* const* d_in, const int* in_sizes, int n_in,
                              void* d_out, int out_size, void* d_ws, size_t ws_size,
                              hipStream_t stream) {
  (void)in_sizes; (void)n_in; (void)out_size; (void)ws_size;
  const float* pair   = (const float*)d_in[0];
  const float* ln_l_g = (const float*)d_in[1];
  const float* ln_l_b = (const float*)d_in[2];
  const float* ln_r_g = (const float*)d_in[3];
  const float* ln_r_b = (const float*)d_in[4];
  const float* Wl = (const float*)d_in[5];
  const float* bl = (const float*)d_in[6];
  const float* Wr = (const float*)d_in[7];
  const float* br = (const float*)d_in[8];
  const float* Wg = (const float*)d_in[9];
  const float* bg = (const float*)d_in[10];
  const float* Wo = (const float*)d_in[11];
  const float* bo = (const float*)d_in[12];
  const float* n_g = (const float*)d_in[13];
  const float* n_b = (const float*)d_in[14];

  char* ws = (char*)d_ws;
  const size_t SZ = (size_t)M_*128*sizeof(u16);         // 37,748,736 B
  u16*  og    = (u16*)(ws);                             // [1152][128][128]
  u16*  gate  = (u16*)(ws + SZ);                        // [1152][128][128]
  u16*  wcat  = (u16*)(ws + 2*SZ);
  float* bcat = (float*)(ws + 2*SZ + 98304);
  float* csum = (float*)(ws + 2*SZ + 98304 + 1536);     // 256 floats
  u16*  wot   = (u16*)(ws + 2*SZ + 98304 + 1536 + 1024);

  // lr[1152][256][128] (left|right cat) lives in d_out (exactly M_*128*4 B),
  // consumed by k_einsum before k_final overwrites d_out with the fp32 result.
  u16* lr = (u16*)d_out;

  k_prep<<<258, 256, 0, stream>>>(ln_l_g, ln_r_g, Wl, Wr, Wg, Wo,
                                  ln_l_b, ln_r_b, bl, br, bg, wcat, wot, bcat, csum);
  k_projln<<<1152, 256, 0, stream>>>(pair, wcat, bcat, csum, lr, gate);
  k_einsum<<<1152, 512, 0, stream>>>(lr, gate, og);
  k_final<<<1152, 512, 0, stream>>>(og, wot, pair, bo, n_g, n_b, (float*)d_out);
}